// Round 14
// baseline (365.220 us; speedup 1.0000x reference)
//
#include <hip/hip_runtime.h>
#include <hip/hip_bf16.h>

#define DIM 128
#define BINSHIFT 8              // 256 nodes per bin
#define BINSZ 256
#define MAXBINS2 400            // 2*NBINS must fit
#define EPB 2048                // edges per block in binscatter
#define CAP 6144                // fixed bin capacity (mean 4082, sigma 64 -> 32 sigma)

typedef __attribute__((ext_vector_type(4))) float f32x4;
typedef __attribute__((ext_vector_type(8))) _Float16 h16x8;
typedef __attribute__((ext_vector_type(2))) _Float16 h16x2;

static __device__ __forceinline__ unsigned short f2h(float f) {
    _Float16 h = (_Float16)f;
    return __builtin_bit_cast(unsigned short, h);
}

#if __has_builtin(__builtin_amdgcn_fdot2)
static __device__ __forceinline__ float dot2(h16x2 a, h16x2 b, float c) {
    return __builtin_amdgcn_fdot2(a, b, c, false);
}
#else
static __device__ __forceinline__ float dot2(h16x2 a, h16x2 b, float c) {
    return c + (float)a.x * (float)b.x + (float)a.y * (float)b.y;
}
#endif

// ---------------------------------------------------------------------------
// Prep: f32->f16 feature convert (both arrays) + weight convert + binCur zero
// ---------------------------------------------------------------------------
struct WPtrs { const float* Wl[4]; const float* Wr[4]; };

__global__ __launch_bounds__(256) void dgnn_prep(
        const float* __restrict__ s, const float* __restrict__ t,
        unsigned short* __restrict__ sb, unsigned short* __restrict__ tb,
        int n4, int cvtb, WPtrs wp, unsigned short* __restrict__ Wc, int wbase,
        int* __restrict__ binCur, int nb2) {
    int b = blockIdx.x;
    if (b < wbase) {
        int which = (b >= cvtb) ? 1 : 0;
        int i = (b - which * cvtb) * 256 + threadIdx.x;
        if (i >= n4) return;
        const float* src = which ? t : s;
        unsigned short* dst = which ? tb : sb;
        float4 v = ((const float4*)src)[i];
        ushort4 o;
        o.x = f2h(v.x); o.y = f2h(v.y); o.z = f2h(v.z); o.w = f2h(v.w);
        ((ushort4*)dst)[i] = o;
    } else if (b < wbase + 128) {
        int tid = (b - wbase) * 256 + threadIdx.x;    // 0..32767
        int i4 = tid << 2;
        int conv = i4 >> 15;                          // 128*256 per conv
        int rem = i4 & 32767;
        int ch = rem >> 8;
        int k = rem & 255;
        const float* src = (k < 128) ? wp.Wl[conv] : wp.Wr[conv];
        float4 v = *(const float4*)(src + ch * DIM + (k & 127));
        ushort4 o;
        o.x = f2h(v.x); o.y = f2h(v.y); o.z = f2h(v.z); o.w = f2h(v.w);
        *(ushort4*)(Wc + i4) = o;
    } else {
        for (int i = threadIdx.x; i < nb2; i += 256) binCur[i] = 0;
    }
}

// ---------------------------------------------------------------------------
// Binscatter: edges -> fixed-capacity bin-grouped array binned[2*NBINS][CAP].
// Pass 1 reads edges once, stages (packed, w) in LDS; pass 2 scatters from LDS.
// ---------------------------------------------------------------------------
__global__ __launch_bounds__(256) void dgnn_binscatter(const float* __restrict__ ew,
        const int* __restrict__ srcI, const int* __restrict__ dstI,
        int* __restrict__ binCur, int2* __restrict__ binned, int E, int NBINS) {
    __shared__ int hist[MAXBINS2];
    __shared__ int epk[EPB];              // packed (d | s<<16)
    __shared__ int ewb[EPB];              // sigmoid weight bits
    const int nb2 = 2 * NBINS;
    for (int i = threadIdx.x; i < nb2; i += 256) hist[i] = 0;
    __syncthreads();
    int base = blockIdx.x * EPB;
    int end = min(base + EPB, E);
    int cnt = end - base;
    for (int j = threadIdx.x; j < cnt; j += 256) {
        int e = base + j;
        int d = dstI[e], s = srcI[e];
        float x = ew[e];
        float w = 1.0f / (1.0f + expf(-x));
        epk[j] = d | (s << 16);
        ewb[j] = __float_as_int(w);
        atomicAdd(&hist[d >> BINSHIFT], 1);
        atomicAdd(&hist[NBINS + (s >> BINSHIFT)], 1);
    }
    __syncthreads();
    for (int i = threadIdx.x; i < nb2; i += 256) {
        int c = hist[i];
        int st = c ? atomicAdd(&binCur[i], c) : 0;    // claim block's range
        hist[i] = i * CAP + st;                       // global write cursor
    }
    __syncthreads();
    for (int j = threadIdx.x; j < cnt; j += 256) {
        int pk = epk[j];
        int wb = ewb[j];
        int d = pk & 0xffff, s = (pk >> 16) & 0xffff;
        int pd = atomicAdd(&hist[d >> BINSHIFT], 1);
        binned[pd] = make_int2(pk, wb);
        int ps = atomicAdd(&hist[NBINS + (s >> BINSHIFT)], 1);
        binned[ps] = make_int2(pk, wb);
    }
}

// ---------------------------------------------------------------------------
// CSR finalize: one block per bin; per-node offsets via 256-wide scan.
// Final CSR entry is 4B: nbr | (w_f16 << 16).
// ---------------------------------------------------------------------------
__global__ __launch_bounds__(256) void dgnn_csrfinal(const int2* __restrict__ binned,
        const int* __restrict__ binCur,
        int* __restrict__ offsD, int* __restrict__ degD,
        int* __restrict__ offsS, int* __restrict__ degS,
        unsigned int* __restrict__ nbrPD, unsigned int* __restrict__ nbrPS,
        int N, int NBINS) {
    int b = blockIdx.x;
    bool isD = b < NBINS;
    int lb = isD ? b : b - NBINS;
    int nodeBase = lb << BINSHIFT;
    const int2* bin = binned + (size_t)b * CAP;
    int K = binCur[b]; if (K > CAP) K = CAP;
    int* offs = isD ? offsD : offsS;
    int* dga  = isD ? degD : degS;
    unsigned int* out = (isD ? nbrPD : nbrPS) + (size_t)lb * CAP;

    __shared__ int cnt[BINSZ], cur[BINSZ], scanb[BINSZ];
    cnt[threadIdx.x] = 0;
    __syncthreads();
    for (int i = threadIdx.x; i < K; i += 256) {
        int pk = bin[i].x;
        int node = isD ? (pk & 0xffff) : ((pk >> 16) & 0xffff);
        atomicAdd(&cnt[node - nodeBase], 1);
    }
    __syncthreads();
    int v = cnt[threadIdx.x];
    scanb[threadIdx.x] = v;
    __syncthreads();
#pragma unroll
    for (int o = 1; o < 256; o <<= 1) {
        int u = (threadIdx.x >= o) ? scanb[threadIdx.x - o] : 0;
        __syncthreads();
        scanb[threadIdx.x] += u;
        __syncthreads();
    }
    int pos = scanb[threadIdx.x] - v;     // local exclusive prefix
    cur[threadIdx.x] = pos;
    int n = nodeBase + threadIdx.x;
    if (n < N) { offs[n] = lb * CAP + pos; dga[n] = v; }
    __syncthreads();
    for (int i = threadIdx.x; i < K; i += 256) {
        int2 en = bin[i];
        int node, nbr;
        if (isD) { node = en.x & 0xffff; nbr = (en.x >> 16) & 0xffff; }
        else     { node = (en.x >> 16) & 0xffff; nbr = en.x & 0xffff; }
        int p = atomicAdd(&cur[node - nodeBase], 1);
        unsigned short wh = f2h(__int_as_float(en.y));
        out[p] = (unsigned int)nbr | ((unsigned int)wh << 16);
    }
}

// ---------------------------------------------------------------------------
// XCD-sliced D+S aggregation (f16). blockIdx%8 = (dir<<2)|j targets one XCD
// per (direction, 64B row-slice j): each XCD re-reads only a 3.2MB slice of
// one feature array -> L2-resident. One wave per (node, slice): 4 groups x
// 16 lanes x 4B = exactly one cache line per edge row-slice.
// ---------------------------------------------------------------------------
__global__ __launch_bounds__(256, 8) void dgnn_gather3(
        const unsigned short* __restrict__ xbD, const int* __restrict__ offsD,
        const int* __restrict__ degD, const unsigned int* __restrict__ nbrD,
        unsigned short* __restrict__ meanD,
        const unsigned short* __restrict__ xbS, const int* __restrict__ offsS,
        const int* __restrict__ degS, const unsigned int* __restrict__ nbrS,
        unsigned short* __restrict__ meanS,
        int N) {
    const int sel = blockIdx.x & 7;
    const int dir = sel >> 2;            // 0 = D, 1 = S
    const int j   = sel & 3;             // 64B slice of the 256B row
    const unsigned short* xb = dir ? xbS : xbD;
    const int* offs          = dir ? offsS : offsD;
    const int* dga           = dir ? degS : degD;
    const unsigned int* nbrP = dir ? nbrS : nbrD;
    unsigned short* meanb    = dir ? meanS : meanD;

    const int wid  = threadIdx.x >> 6;
    const int lane = threadIdx.x & 63;
    const int n = (blockIdx.x >> 3) * 4 + wid;
    if (n >= N) return;
    const int g4 = lane >> 4;            // edge-pair group 0..3
    const int c  = lane & 15;            // 4B chunk within the 64B slice

    const int beg = offs[n];
    const int dg  = dga[n];
    const int end = beg + dg;
    const size_t chOff = (size_t)(j << 5) + (c << 1);   // element offset

    float a0 = 0.f, a1 = 0.f;

    for (int base = beg; base < end; base += 64) {
        int cnt = end - base; if (cnt > 64) cnt = 64;
        unsigned int pk_l = (base + lane < end) ? nbrP[base + lane] : 0u;

        for (int it = 0; it < cnt; it += 16) {
            // group g4: pairs (e,e+1) at e = it+2*g4 and e+8; pads carry w=0
            int e0 = it + (g4 << 1);
            unsigned int pa = __shfl(pk_l, e0, 64);
            unsigned int pb = __shfl(pk_l, e0 + 1, 64);
            unsigned int pc = __shfl(pk_l, e0 + 8, 64);
            unsigned int pd = __shfl(pk_l, e0 + 9, 64);
            unsigned int va = *(const unsigned int*)(xb + ((size_t)(pa & 0xffffu) << 7) + chOff);
            unsigned int vb = *(const unsigned int*)(xb + ((size_t)(pb & 0xffffu) << 7) + chOff);
            unsigned int vc = *(const unsigned int*)(xb + ((size_t)(pc & 0xffffu) << 7) + chOff);
            unsigned int vd = *(const unsigned int*)(xb + ((size_t)(pd & 0xffffu) << 7) + chOff);
            h16x2 wp0 = __builtin_bit_cast(h16x2, __builtin_amdgcn_perm(pb, pa, 0x07060302u));
            h16x2 wp1 = __builtin_bit_cast(h16x2, __builtin_amdgcn_perm(pd, pc, 0x07060302u));
            h16x2 lo0 = __builtin_bit_cast(h16x2, __builtin_amdgcn_perm(vb, va, 0x05040100u));
            h16x2 hi0 = __builtin_bit_cast(h16x2, __builtin_amdgcn_perm(vb, va, 0x07060302u));
            h16x2 lo1 = __builtin_bit_cast(h16x2, __builtin_amdgcn_perm(vd, vc, 0x05040100u));
            h16x2 hi1 = __builtin_bit_cast(h16x2, __builtin_amdgcn_perm(vd, vc, 0x07060302u));
            a0 = dot2(wp0, lo0, a0);
            a1 = dot2(wp0, hi0, a1);
            a0 = dot2(wp1, lo1, a0);
            a1 = dot2(wp1, hi1, a1);
        }
    }

    // combine the 4 groups
    a0 += __shfl_xor(a0, 16); a0 += __shfl_xor(a0, 32);
    a1 += __shfl_xor(a1, 16); a1 += __shfl_xor(a1, 32);

    if (lane < 16) {
        float inv = 1.0f / fmaxf((float)dg, 1.0f);
        unsigned int o = (unsigned int)f2h(a0 * inv)
                       | ((unsigned int)f2h(a1 * inv) << 16);
        *(unsigned int*)(meanb + ((size_t)n << 7) + chOff) = o;
    }
}

// ---------------------------------------------------------------------------
// Fused pair of node GEMMs via f16 MFMA, weight-stationary LDS (XOR-swizzled).
// ---------------------------------------------------------------------------
__global__ __launch_bounds__(256) void dgnn_node2(
        const unsigned short* __restrict__ meanA, const unsigned short* __restrict__ xbA,
        const unsigned short* __restrict__ WcA, const float* __restrict__ biasA,
        float* __restrict__ outfA, unsigned short* __restrict__ outbA,
        const unsigned short* __restrict__ meanB, const unsigned short* __restrict__ xbB,
        const unsigned short* __restrict__ WcB, const float* __restrict__ biasB,
        float* __restrict__ outfB, unsigned short* __restrict__ outbB,
        int N, int mode, int halfb) {
    __shared__ __align__(16) unsigned short sW[128 * 256];   // 64KB

    int which = (blockIdx.x >= halfb) ? 1 : 0;
    const unsigned short* meanb = which ? meanB : meanA;
    const unsigned short* xb    = which ? xbB : xbA;
    const unsigned short* Wc    = which ? WcB : WcA;
    const float* bias           = which ? biasB : biasA;
    float* outf                 = which ? outfB : outfA;
    unsigned short* outb        = which ? outbB : outbA;
    int lb = blockIdx.x - which * halfb;

    // ---- stage Wc (swizzled): 4096 16B chunks, coalesced reads
    for (int i = threadIdx.x; i < 4096; i += 256) {
        int ch = i >> 5;                 // 32 chunks per 512B row
        int off = (i & 31) << 4;
        float4 v = *(const float4*)((const char*)Wc + ((size_t)i << 4));
        int soff = off ^ ((ch & 7) << 4);
        *(float4*)((char*)sW + ch * 512 + soff) = v;
    }
    __syncthreads();

    const int wid = threadIdx.x >> 6;
    const int lane = threadIdx.x & 63;
    const int r = lane & 15;
    const int q = lane >> 4;
    const int ntiles = (N + 15) >> 4;

    for (int tile = lb * 4 + wid; tile < ntiles; tile += halfb * 4) {
        const int n0 = tile << 4;
        const unsigned short* A0 = meanb + (size_t)(n0 + r) * DIM + q * 8;
        const unsigned short* A1 = xb    + (size_t)(n0 + r) * DIM + q * 8;

        f32x4 acc[8];
#pragma unroll
        for (int ct = 0; ct < 8; ct++) acc[ct] = (f32x4){0.f, 0.f, 0.f, 0.f};

#pragma unroll
        for (int ks = 0; ks < 8; ks++) {
            h16x8 a = (ks < 4) ? *(const h16x8*)(A0 + ks * 32)
                               : *(const h16x8*)(A1 + (ks - 4) * 32);
#pragma unroll
            for (int ct = 0; ct < 8; ct++) {
                int ch = ct * 16 + r;
                int soff = (ks * 64 + q * 16) ^ ((ch & 7) << 4);
                h16x8 b = *(const h16x8*)((const char*)sW + ch * 512 + soff);
                acc[ct] = __builtin_amdgcn_mfma_f32_16x16x32_f16(a, b, acc[ct], 0, 0, 0);
            }
        }

#pragma unroll
        for (int ct = 0; ct < 8; ct++) {
            int ch = ct * 16 + r;
            float bv = bias[ch];
#pragma unroll
            for (int rr = 0; rr < 4; rr++) {
                int n = n0 + q * 4 + rr;
                if (n >= N) break;
                float v = acc[ct][rr] + bv;
                if (mode) {
                    v = fmaxf(v, 0.f);
                    outb[(size_t)n * DIM + ch] = f2h(v);
                } else {
                    outf[(size_t)n * DIM + ch] = v;
                }
            }
        }
    }
}

// ---------------------------------------------------------------------------
extern "C" void kernel_launch(void* const* d_in, const int* in_sizes, int n_in,
                              void* d_out, int out_size, void* d_ws, size_t ws_size,
                              hipStream_t stream) {
    const float* s  = (const float*)d_in[0];
    const float* t  = (const float*)d_in[1];
    const int*   ei = (const int*)d_in[2];   // [2,E] int32 per harness ABI
    const float* ew = (const float*)d_in[3];
    const float* s0_Wl = (const float*)d_in[4];
    const float* s0_bl = (const float*)d_in[5];
    const float* s0_Wr = (const float*)d_in[6];
    const float* t0_Wl = (const float*)d_in[7];
    const float* t0_bl = (const float*)d_in[8];
    const float* t0_Wr = (const float*)d_in[9];
    const float* s1_Wl = (const float*)d_in[10];
    const float* s1_bl = (const float*)d_in[11];
    const float* s1_Wr = (const float*)d_in[12];
    const float* t1_Wl = (const float*)d_in[13];
    const float* t1_bl = (const float*)d_in[14];
    const float* t1_Wr = (const float*)d_in[15];

    const int N = in_sizes[0] / DIM;
    const int E = in_sizes[3];
    const int NBINS = (N + BINSZ - 1) / BINSZ;

    // ---- workspace carve-up
    unsigned int* nbrPD = (unsigned int*)d_ws;          // [NBINS*CAP] packed
    unsigned int* nbrPS = nbrPD + (size_t)NBINS * CAP;  // [NBINS*CAP]
    unsigned short* up = (unsigned short*)(nbrPS + (size_t)NBINS * CAP);
    unsigned short* sb    = up;                         // [N*128] f16
    unsigned short* tb    = sb    + (size_t)N * DIM;
    unsigned short* meanA = tb    + (size_t)N * DIM;    // aliased: binned
    unsigned short* meanB = meanA + (size_t)N * DIM;
    unsigned short* s1b   = meanB + (size_t)N * DIM;
    unsigned short* t1b   = s1b   + (size_t)N * DIM;
    unsigned short* Wc    = t1b   + (size_t)N * DIM;    // [4*128*256] f16
    int* ip     = (int*)(Wc + 4 * 128 * 256);
    int* binCur = ip;                                   // [2*NBINS]
    int* offsD  = binCur + 2 * NBINS;                   // [N]
    int* degD   = offsD + N;                            // [N]
    int* offsS  = degD + N;                             // [N]
    int* degS   = offsS + N;                            // [N]

    int2* binned = (int2*)meanA;    // [2*NBINS*CAP] = 19.3MB <= meanA+meanB

    float* sout = (float*)d_out;
    float* tout = sout + (size_t)N * DIM;

    const int* srcI = ei;       // row 0
    const int* dstI = ei + E;   // row 1

    const int binb = (E + EPB - 1) / EPB;
    const int g3 = ((N + 3) >> 2) << 3;                 // (node/4 blocks) x 8 sel
    const int nodeb = 256;                              // per conv; grid 512
    const int cvtb = ((N * DIM / 4) + 255) / 256;

    // ---- prep: f16 conversions (features + weights) + binCur zero, one launch
    WPtrs wp;
    wp.Wl[0] = s0_Wl; wp.Wr[0] = s0_Wr;
    wp.Wl[1] = t0_Wl; wp.Wr[1] = t0_Wr;
    wp.Wl[2] = s1_Wl; wp.Wr[2] = s1_Wr;
    wp.Wl[3] = t1_Wl; wp.Wr[3] = t1_Wr;
    dgnn_prep<<<2 * cvtb + 129, 256, 0, stream>>>(s, t, sb, tb, N * DIM / 4,
                                                  cvtb, wp, Wc, 2 * cvtb,
                                                  binCur, 2 * NBINS);

    // ---- CSR build: fixed-capacity bucket scatter + per-bin finalize
    dgnn_binscatter<<<binb, 256, 0, stream>>>(ew, srcI, dstI, binCur, binned, E, NBINS);
    dgnn_csrfinal<<<2 * NBINS, 256, 0, stream>>>(binned, binCur,
                                                 offsD, degD, offsS, degS,
                                                 nbrPD, nbrPS, N, NBINS);

    // ---- layer 0 (relu, f16 intermediates)
    dgnn_gather3<<<g3, 256, 0, stream>>>(tb, offsD, degD, nbrPD, meanA,
                                         sb, offsS, degS, nbrPS, meanB, N);
    dgnn_node2<<<2 * nodeb, 256, 0, stream>>>(
        meanA, tb, Wc,         s0_bl, nullptr, s1b,
        meanB, sb, Wc + 32768, t0_bl, nullptr, t1b, N, 1, nodeb);

    // ---- layer 1 (f32 outputs)
    dgnn_gather3<<<g3, 256, 0, stream>>>(t1b, offsD, degD, nbrPD, meanA,
                                         s1b, offsS, degS, nbrPS, meanB, N);
    dgnn_node2<<<2 * nodeb, 256, 0, stream>>>(
        meanA, t1b, Wc + 2 * 32768, s1_bl, sout, nullptr,
        meanB, s1b, Wc + 3 * 32768, t1_bl, tout, nullptr, N, 0, nodeb);
}

// Round 16
// 288.126 us; speedup vs baseline: 1.2676x; 1.2676x over previous
//
#include <hip/hip_runtime.h>
#include <hip/hip_bf16.h>

#define DIM 128
#define BINSHIFT 8              // 256 nodes per bin
#define BINSZ 256
#define MAXBINS2 400            // 2*NBINS must fit
#define EPB 2048                // edges per block in binscatter
#define CAP 6144                // fixed bin capacity (mean 4082, sigma 64 -> 32 sigma)

typedef __attribute__((ext_vector_type(4))) float f32x4;
typedef __attribute__((ext_vector_type(8))) _Float16 h16x8;
typedef __attribute__((ext_vector_type(2))) _Float16 h16x2;
typedef __attribute__((ext_vector_type(8))) unsigned short u16x8;
typedef __attribute__((ext_vector_type(4))) unsigned int u32x4;

static __device__ __forceinline__ unsigned short f2h(float f) {
    _Float16 h = (_Float16)f;
    return __builtin_bit_cast(unsigned short, h);
}

#if __has_builtin(__builtin_amdgcn_fdot2)
static __device__ __forceinline__ float dot2(h16x2 a, h16x2 b, float c) {
    return __builtin_amdgcn_fdot2(a, b, c, false);
}
#else
static __device__ __forceinline__ float dot2(h16x2 a, h16x2 b, float c) {
    return c + (float)a.x * (float)b.x + (float)a.y * (float)b.y;
}
#endif

// ---------------------------------------------------------------------------
// Prep: f32->f16 feature convert (both arrays) + weight convert + binCur zero
// ---------------------------------------------------------------------------
struct WPtrs { const float* Wl[4]; const float* Wr[4]; };

__global__ __launch_bounds__(256) void dgnn_prep(
        const float* __restrict__ s, const float* __restrict__ t,
        unsigned short* __restrict__ sb, unsigned short* __restrict__ tb,
        int n4, int cvtb, WPtrs wp, unsigned short* __restrict__ Wc, int wbase,
        int* __restrict__ binCur, int nb2) {
    int b = blockIdx.x;
    if (b < wbase) {
        int which = (b >= cvtb) ? 1 : 0;
        int i = (b - which * cvtb) * 256 + threadIdx.x;
        if (i >= n4) return;
        const float* src = which ? t : s;
        unsigned short* dst = which ? tb : sb;
        float4 v = ((const float4*)src)[i];
        ushort4 o;
        o.x = f2h(v.x); o.y = f2h(v.y); o.z = f2h(v.z); o.w = f2h(v.w);
        ((ushort4*)dst)[i] = o;
    } else if (b < wbase + 128) {
        int tid = (b - wbase) * 256 + threadIdx.x;    // 0..32767
        int i4 = tid << 2;
        int conv = i4 >> 15;                          // 128*256 per conv
        int rem = i4 & 32767;
        int ch = rem >> 8;
        int k = rem & 255;
        const float* src = (k < 128) ? wp.Wl[conv] : wp.Wr[conv];
        float4 v = *(const float4*)(src + ch * DIM + (k & 127));
        ushort4 o;
        o.x = f2h(v.x); o.y = f2h(v.y); o.z = f2h(v.z); o.w = f2h(v.w);
        *(ushort4*)(Wc + i4) = o;
    } else {
        for (int i = threadIdx.x; i < nb2; i += 256) binCur[i] = 0;
    }
}

// ---------------------------------------------------------------------------
// Binscatter: edges -> fixed-capacity bin-grouped array binned[2*NBINS][CAP].
// Pass 1 reads edges once, stages (packed, w) in LDS; pass 2 scatters from LDS.
// ---------------------------------------------------------------------------
__global__ __launch_bounds__(256) void dgnn_binscatter(const float* __restrict__ ew,
        const int* __restrict__ srcI, const int* __restrict__ dstI,
        int* __restrict__ binCur, int2* __restrict__ binned, int E, int NBINS) {
    __shared__ int hist[MAXBINS2];
    __shared__ int epk[EPB];              // packed (d | s<<16)
    __shared__ int ewb[EPB];              // sigmoid weight bits
    const int nb2 = 2 * NBINS;
    for (int i = threadIdx.x; i < nb2; i += 256) hist[i] = 0;
    __syncthreads();
    int base = blockIdx.x * EPB;
    int end = min(base + EPB, E);
    int cnt = end - base;
    for (int j = threadIdx.x; j < cnt; j += 256) {
        int e = base + j;
        int d = dstI[e], s = srcI[e];
        float x = ew[e];
        float w = 1.0f / (1.0f + expf(-x));
        epk[j] = d | (s << 16);
        ewb[j] = __float_as_int(w);
        atomicAdd(&hist[d >> BINSHIFT], 1);
        atomicAdd(&hist[NBINS + (s >> BINSHIFT)], 1);
    }
    __syncthreads();
    for (int i = threadIdx.x; i < nb2; i += 256) {
        int c = hist[i];
        int st = c ? atomicAdd(&binCur[i], c) : 0;    // claim block's range
        hist[i] = i * CAP + st;                       // global write cursor
    }
    __syncthreads();
    for (int j = threadIdx.x; j < cnt; j += 256) {
        int pk = epk[j];
        int wb = ewb[j];
        int d = pk & 0xffff, s = (pk >> 16) & 0xffff;
        int pd = atomicAdd(&hist[d >> BINSHIFT], 1);
        binned[pd] = make_int2(pk, wb);
        int ps = atomicAdd(&hist[NBINS + (s >> BINSHIFT)], 1);
        binned[ps] = make_int2(pk, wb);
    }
}

// ---------------------------------------------------------------------------
// CSR finalize: one block per bin; per-node offsets via 256-wide scan.
// Final CSR entry is 4B: nbr | (w_f16 << 16).
// ---------------------------------------------------------------------------
__global__ __launch_bounds__(256) void dgnn_csrfinal(const int2* __restrict__ binned,
        const int* __restrict__ binCur,
        int* __restrict__ offsD, int* __restrict__ degD,
        int* __restrict__ offsS, int* __restrict__ degS,
        unsigned int* __restrict__ nbrPD, unsigned int* __restrict__ nbrPS,
        int N, int NBINS) {
    int b = blockIdx.x;
    bool isD = b < NBINS;
    int lb = isD ? b : b - NBINS;
    int nodeBase = lb << BINSHIFT;
    const int2* bin = binned + (size_t)b * CAP;
    int K = binCur[b]; if (K > CAP) K = CAP;
    int* offs = isD ? offsD : offsS;
    int* dga  = isD ? degD : degS;
    unsigned int* out = (isD ? nbrPD : nbrPS) + (size_t)lb * CAP;

    __shared__ int cnt[BINSZ], cur[BINSZ], scanb[BINSZ];
    cnt[threadIdx.x] = 0;
    __syncthreads();
    for (int i = threadIdx.x; i < K; i += 256) {
        int pk = bin[i].x;
        int node = isD ? (pk & 0xffff) : ((pk >> 16) & 0xffff);
        atomicAdd(&cnt[node - nodeBase], 1);
    }
    __syncthreads();
    int v = cnt[threadIdx.x];
    scanb[threadIdx.x] = v;
    __syncthreads();
#pragma unroll
    for (int o = 1; o < 256; o <<= 1) {
        int u = (threadIdx.x >= o) ? scanb[threadIdx.x - o] : 0;
        __syncthreads();
        scanb[threadIdx.x] += u;
        __syncthreads();
    }
    int pos = scanb[threadIdx.x] - v;     // local exclusive prefix
    cur[threadIdx.x] = pos;
    int n = nodeBase + threadIdx.x;
    if (n < N) { offs[n] = lb * CAP + pos; dga[n] = v; }
    __syncthreads();
    for (int i = threadIdx.x; i < K; i += 256) {
        int2 en = bin[i];
        int node, nbr;
        if (isD) { node = en.x & 0xffff; nbr = (en.x >> 16) & 0xffff; }
        else     { node = (en.x >> 16) & 0xffff; nbr = en.x & 0xffff; }
        int p = atomicAdd(&cur[node - nodeBase], 1);
        unsigned short wh = f2h(__int_as_float(en.y));
        out[p] = (unsigned int)nbr | ((unsigned int)wh << 16);
    }
}

// ---------------------------------------------------------------------------
// Fused D+S aggregation (f16): one HALF-WAVE per node; packed 4B CSR entries.
// Main loop: 16 edges, 8 rows in flight per 16-lane group (nontemporal:
// random rows have no L1 reuse). Tail loop: 4 edges.
// ---------------------------------------------------------------------------
__global__ __launch_bounds__(256, 8) void dgnn_gather2(
        const unsigned short* __restrict__ xbD, const int* __restrict__ offsD,
        const int* __restrict__ degD, const unsigned int* __restrict__ nbrD,
        unsigned short* __restrict__ meanD,
        const unsigned short* __restrict__ xbS, const int* __restrict__ offsS,
        const int* __restrict__ degS, const unsigned int* __restrict__ nbrS,
        unsigned short* __restrict__ meanS,
        int N, int halfb) {
    int which = (blockIdx.x >= halfb) ? 1 : 0;
    const unsigned short* xb = which ? xbS : xbD;
    const int* offs          = which ? offsS : offsD;
    const int* dga           = which ? degS : degD;
    const unsigned int* nbrP = which ? nbrS : nbrD;
    unsigned short* meanb    = which ? meanS : meanD;

    long long gid = (long long)(blockIdx.x - which * halfb) * 256 + threadIdx.x;
    int n = (int)(gid >> 5);             // half-wave index = node
    if (n >= N) return;
    const int l32 = (int)gid & 31;       // lane within half
    const int q2  = l32 >> 4;            // group 0/1 (pair parity)
    const int m   = l32 & 15;            // channels m*8 .. m*8+7

    int beg = offs[n];
    int dg  = dga[n];
    int end = beg + dg;
    float acc[8];
#pragma unroll
    for (int k = 0; k < 8; k++) acc[k] = 0.f;

    for (int base = beg; base < end; base += 32) {
        int cnt = end - base; if (cnt > 32) cnt = 32;
        bool inb = (base + l32) < end;
        unsigned int pk_l = inb ? nbrP[base + l32] : 0u;   // nbr | w_f16<<16

        int it = 0;
        for (; it + 16 <= cnt; it += 16) {
            // group q2 handles pairs (e,e+1) at e = it+2*q2 + {0,4,8,12}
            int e0 = it + (q2 << 1);
            unsigned int p[8];
#pragma unroll
            for (int j = 0; j < 4; j++) {
                p[2 * j]     = __shfl(pk_l, e0 + 4 * j, 32);
                p[2 * j + 1] = __shfl(pk_l, e0 + 4 * j + 1, 32);
            }
            u32x4 v[8];
#pragma unroll
            for (int j = 0; j < 8; j++)
                v[j] = __builtin_nontemporal_load(
                    (const u32x4*)(xb + ((size_t)(p[j] & 0xffffu) << 7) + (m << 3)));
#pragma unroll
            for (int j = 0; j < 4; j++) {
                h16x2 wp = __builtin_bit_cast(h16x2,
                    __builtin_amdgcn_perm(p[2 * j + 1], p[2 * j], 0x07060302u));
#pragma unroll
                for (int k = 0; k < 4; k++) {
                    unsigned int ua = v[2 * j][k];
                    unsigned int ub = v[2 * j + 1][k];
                    h16x2 lo = __builtin_bit_cast(h16x2,
                        __builtin_amdgcn_perm(ub, ua, 0x05040100u));
                    h16x2 hi = __builtin_bit_cast(h16x2,
                        __builtin_amdgcn_perm(ub, ua, 0x07060302u));
                    acc[2 * k]     = dot2(wp, lo, acc[2 * k]);
                    acc[2 * k + 1] = dot2(wp, hi, acc[2 * k + 1]);
                }
            }
        }
        for (; it < cnt; it += 4) {      // 4-edge tail: 1 pair per group
            int e0 = it + (q2 << 1);     // pad lanes carry w=0, safe
            unsigned int pa = __shfl(pk_l, e0, 32);
            unsigned int pb = __shfl(pk_l, e0 + 1, 32);
            u32x4 va = __builtin_nontemporal_load(
                (const u32x4*)(xb + ((size_t)(pa & 0xffffu) << 7) + (m << 3)));
            u32x4 vb = __builtin_nontemporal_load(
                (const u32x4*)(xb + ((size_t)(pb & 0xffffu) << 7) + (m << 3)));
            h16x2 wp = __builtin_bit_cast(h16x2,
                __builtin_amdgcn_perm(pb, pa, 0x07060302u));
#pragma unroll
            for (int k = 0; k < 4; k++) {
                h16x2 lo = __builtin_bit_cast(h16x2,
                    __builtin_amdgcn_perm(vb[k], va[k], 0x05040100u));
                h16x2 hi = __builtin_bit_cast(h16x2,
                    __builtin_amdgcn_perm(vb[k], va[k], 0x07060302u));
                acc[2 * k]     = dot2(wp, lo, acc[2 * k]);
                acc[2 * k + 1] = dot2(wp, hi, acc[2 * k + 1]);
            }
        }
    }

#pragma unroll
    for (int k = 0; k < 8; k++)
        acc[k] += __shfl_xor(acc[k], 16);    // combine the two 16-groups

    if (q2 == 0) {
        float inv = 1.0f / fmaxf((float)dg, 1.0f);
        u16x8 o;
#pragma unroll
        for (int k = 0; k < 8; k++) o[k] = f2h(acc[k] * inv);
        *(u16x8*)(meanb + ((size_t)n << 7) + (m << 3)) = o;
    }
}

// ---------------------------------------------------------------------------
// Fused pair of node GEMMs via f16 MFMA, weight-stationary LDS (XOR-swizzled).
// ---------------------------------------------------------------------------
__global__ __launch_bounds__(256) void dgnn_node2(
        const unsigned short* __restrict__ meanA, const unsigned short* __restrict__ xbA,
        const unsigned short* __restrict__ WcA, const float* __restrict__ biasA,
        float* __restrict__ outfA, unsigned short* __restrict__ outbA,
        const unsigned short* __restrict__ meanB, const unsigned short* __restrict__ xbB,
        const unsigned short* __restrict__ WcB, const float* __restrict__ biasB,
        float* __restrict__ outfB, unsigned short* __restrict__ outbB,
        int N, int mode, int halfb) {
    __shared__ __align__(16) unsigned short sW[128 * 256];   // 64KB

    int which = (blockIdx.x >= halfb) ? 1 : 0;
    const unsigned short* meanb = which ? meanB : meanA;
    const unsigned short* xb    = which ? xbB : xbA;
    const unsigned short* Wc    = which ? WcB : WcA;
    const float* bias           = which ? biasB : biasA;
    float* outf                 = which ? outfB : outfA;
    unsigned short* outb        = which ? outbB : outbA;
    int lb = blockIdx.x - which * halfb;

    // ---- stage Wc (swizzled): 4096 16B chunks, coalesced reads
    for (int i = threadIdx.x; i < 4096; i += 256) {
        int ch = i >> 5;                 // 32 chunks per 512B row
        int off = (i & 31) << 4;
        float4 v = *(const float4*)((const char*)Wc + ((size_t)i << 4));
        int soff = off ^ ((ch & 7) << 4);
        *(float4*)((char*)sW + ch * 512 + soff) = v;
    }
    __syncthreads();

    const int wid = threadIdx.x >> 6;
    const int lane = threadIdx.x & 63;
    const int r = lane & 15;
    const int q = lane >> 4;
    const int ntiles = (N + 15) >> 4;

    for (int tile = lb * 4 + wid; tile < ntiles; tile += halfb * 4) {
        const int n0 = tile << 4;
        const unsigned short* A0 = meanb + (size_t)(n0 + r) * DIM + q * 8;
        const unsigned short* A1 = xb    + (size_t)(n0 + r) * DIM + q * 8;

        f32x4 acc[8];
#pragma unroll
        for (int ct = 0; ct < 8; ct++) acc[ct] = (f32x4){0.f, 0.f, 0.f, 0.f};

#pragma unroll
        for (int ks = 0; ks < 8; ks++) {
            h16x8 a = (ks < 4) ? *(const h16x8*)(A0 + ks * 32)
                               : *(const h16x8*)(A1 + (ks - 4) * 32);
#pragma unroll
            for (int ct = 0; ct < 8; ct++) {
                int ch = ct * 16 + r;
                int soff = (ks * 64 + q * 16) ^ ((ch & 7) << 4);
                h16x8 b = *(const h16x8*)((const char*)sW + ch * 512 + soff);
                acc[ct] = __builtin_amdgcn_mfma_f32_16x16x32_f16(a, b, acc[ct], 0, 0, 0);
            }
        }

#pragma unroll
        for (int ct = 0; ct < 8; ct++) {
            int ch = ct * 16 + r;
            float bv = bias[ch];
#pragma unroll
            for (int rr = 0; rr < 4; rr++) {
                int n = n0 + q * 4 + rr;
                if (n >= N) break;
                float v = acc[ct][rr] + bv;
                if (mode) {
                    v = fmaxf(v, 0.f);
                    outb[(size_t)n * DIM + ch] = f2h(v);
                } else {
                    outf[(size_t)n * DIM + ch] = v;
                }
            }
        }
    }
}

// ---------------------------------------------------------------------------
extern "C" void kernel_launch(void* const* d_in, const int* in_sizes, int n_in,
                              void* d_out, int out_size, void* d_ws, size_t ws_size,
                              hipStream_t stream) {
    const float* s  = (const float*)d_in[0];
    const float* t  = (const float*)d_in[1];
    const int*   ei = (const int*)d_in[2];   // [2,E] int32 per harness ABI
    const float* ew = (const float*)d_in[3];
    const float* s0_Wl = (const float*)d_in[4];
    const float* s0_bl = (const float*)d_in[5];
    const float* s0_Wr = (const float*)d_in[6];
    const float* t0_Wl = (const float*)d_in[7];
    const float* t0_bl = (const float*)d_in[8];
    const float* t0_Wr = (const float*)d_in[9];
    const float* s1_Wl = (const float*)d_in[10];
    const float* s1_bl = (const float*)d_in[11];
    const float* s1_Wr = (const float*)d_in[12];
    const float* t1_Wl = (const float*)d_in[13];
    const float* t1_bl = (const float*)d_in[14];
    const float* t1_Wr = (const float*)d_in[15];

    const int N = in_sizes[0] / DIM;
    const int E = in_sizes[3];
    const int NBINS = (N + BINSZ - 1) / BINSZ;

    // ---- workspace carve-up
    unsigned int* nbrPD = (unsigned int*)d_ws;          // [NBINS*CAP] packed
    unsigned int* nbrPS = nbrPD + (size_t)NBINS * CAP;  // [NBINS*CAP]
    unsigned short* up = (unsigned short*)(nbrPS + (size_t)NBINS * CAP);
    unsigned short* sb    = up;                         // [N*128] f16
    unsigned short* tb    = sb    + (size_t)N * DIM;
    unsigned short* meanA = tb    + (size_t)N * DIM;    // aliased: binned
    unsigned short* meanB = meanA + (size_t)N * DIM;
    unsigned short* s1b   = meanB + (size_t)N * DIM;
    unsigned short* t1b   = s1b   + (size_t)N * DIM;
    unsigned short* Wc    = t1b   + (size_t)N * DIM;    // [4*128*256] f16
    int* ip     = (int*)(Wc + 4 * 128 * 256);
    int* binCur = ip;                                   // [2*NBINS]
    int* offsD  = binCur + 2 * NBINS;                   // [N]
    int* degD   = offsD + N;                            // [N]
    int* offsS  = degD + N;                             // [N]
    int* degS   = offsS + N;                            // [N]

    int2* binned = (int2*)meanA;    // [2*NBINS*CAP] = 19.3MB <= meanA+meanB

    float* sout = (float*)d_out;
    float* tout = sout + (size_t)N * DIM;

    const int* srcI = ei;       // row 0
    const int* dstI = ei + E;   // row 1

    const int binb = (E + EPB - 1) / EPB;
    const int gbH = (int)(((long long)N * 32 + 255) / 256);   // half-wave/node
    const int nodeb = 256;                              // per conv; grid 512
    const int cvtb = ((N * DIM / 4) + 255) / 256;

    // ---- prep: f16 conversions (features + weights) + binCur zero, one launch
    WPtrs wp;
    wp.Wl[0] = s0_Wl; wp.Wr[0] = s0_Wr;
    wp.Wl[1] = t0_Wl; wp.Wr[1] = t0_Wr;
    wp.Wl[2] = s1_Wl; wp.Wr[2] = s1_Wr;
    wp.Wl[3] = t1_Wl; wp.Wr[3] = t1_Wr;
    dgnn_prep<<<2 * cvtb + 129, 256, 0, stream>>>(s, t, sb, tb, N * DIM / 4,
                                                  cvtb, wp, Wc, 2 * cvtb,
                                                  binCur, 2 * NBINS);

    // ---- CSR build: fixed-capacity bucket scatter + per-bin finalize
    dgnn_binscatter<<<binb, 256, 0, stream>>>(ew, srcI, dstI, binCur, binned, E, NBINS);
    dgnn_csrfinal<<<2 * NBINS, 256, 0, stream>>>(binned, binCur,
                                                 offsD, degD, offsS, degS,
                                                 nbrPD, nbrPS, N, NBINS);

    // ---- layer 0 (relu, f16 intermediates)
    dgnn_gather2<<<2 * gbH, 256, 0, stream>>>(tb, offsD, degD, nbrPD, meanA,
                                              sb, offsS, degS, nbrPS, meanB, N, gbH);
    dgnn_node2<<<2 * nodeb, 256, 0, stream>>>(
        meanA, tb, Wc,         s0_bl, nullptr, s1b,
        meanB, sb, Wc + 32768, t0_bl, nullptr, t1b, N, 1, nodeb);

    // ---- layer 1 (f32 outputs)
    dgnn_gather2<<<2 * gbH, 256, 0, stream>>>(t1b, offsD, degD, nbrPD, meanA,
                                              s1b, offsS, degS, nbrPS, meanB, N, gbH);
    dgnn_node2<<<2 * nodeb, 256, 0, stream>>>(
        meanA, t1b, Wc + 2 * 32768, s1_bl, sout, nullptr,
        meanB, s1b, Wc + 3 * 32768, t1_bl, tout, nullptr, N, 0, nodeb);
}

// Round 17
// 227.071 us; speedup vs baseline: 1.6084x; 1.2689x over previous
//
#include <hip/hip_runtime.h>
#include <hip/hip_bf16.h>

#define DIM 128
#define BINSHIFT 8              // 256 nodes per bin
#define BINSZ 256
#define MAXBINS2 400            // 2*NBINS must fit
#define EPB 2048                // edges per block in binscatter
#define CAP 6144                // fixed bin capacity (mean 4082, sigma 64 -> 32 sigma)

typedef __attribute__((ext_vector_type(4))) float f32x4;
typedef __attribute__((ext_vector_type(8))) _Float16 h16x8;
typedef __attribute__((ext_vector_type(2))) _Float16 h16x2;
typedef __attribute__((ext_vector_type(8))) unsigned short u16x8;
typedef __attribute__((ext_vector_type(4))) unsigned int u32x4;

static __device__ __forceinline__ unsigned short f2h(float f) {
    _Float16 h = (_Float16)f;
    return __builtin_bit_cast(unsigned short, h);
}

#if __has_builtin(__builtin_amdgcn_fdot2)
static __device__ __forceinline__ float dot2(h16x2 a, h16x2 b, float c) {
    return __builtin_amdgcn_fdot2(a, b, c, false);
}
#else
static __device__ __forceinline__ float dot2(h16x2 a, h16x2 b, float c) {
    return c + (float)a.x * (float)b.x + (float)a.y * (float)b.y;
}
#endif

// ---------------------------------------------------------------------------
// Prep: f32->f16 feature convert (both arrays) + weight convert + binCur zero
// ---------------------------------------------------------------------------
struct WPtrs { const float* Wl[4]; const float* Wr[4]; };

__global__ __launch_bounds__(256) void dgnn_prep(
        const float* __restrict__ s, const float* __restrict__ t,
        unsigned short* __restrict__ sb, unsigned short* __restrict__ tb,
        int n4, int cvtb, WPtrs wp, unsigned short* __restrict__ Wc, int wbase,
        int* __restrict__ binCur, int nb2) {
    int b = blockIdx.x;
    if (b < wbase) {
        int which = (b >= cvtb) ? 1 : 0;
        int i = (b - which * cvtb) * 256 + threadIdx.x;
        if (i >= n4) return;
        const float* src = which ? t : s;
        unsigned short* dst = which ? tb : sb;
        float4 v = ((const float4*)src)[i];
        ushort4 o;
        o.x = f2h(v.x); o.y = f2h(v.y); o.z = f2h(v.z); o.w = f2h(v.w);
        ((ushort4*)dst)[i] = o;
    } else if (b < wbase + 128) {
        int tid = (b - wbase) * 256 + threadIdx.x;    // 0..32767
        int i4 = tid << 2;
        int conv = i4 >> 15;                          // 128*256 per conv
        int rem = i4 & 32767;
        int ch = rem >> 8;
        int k = rem & 255;
        const float* src = (k < 128) ? wp.Wl[conv] : wp.Wr[conv];
        float4 v = *(const float4*)(src + ch * DIM + (k & 127));
        ushort4 o;
        o.x = f2h(v.x); o.y = f2h(v.y); o.z = f2h(v.z); o.w = f2h(v.w);
        *(ushort4*)(Wc + i4) = o;
    } else {
        for (int i = threadIdx.x; i < nb2; i += 256) binCur[i] = 0;
    }
}

// ---------------------------------------------------------------------------
// Binscatter: edges -> fixed-capacity bin-grouped array binned[2*NBINS][CAP].
// Pass 1 reads edges once, stages (packed, w) in LDS; pass 2 scatters from LDS.
// ---------------------------------------------------------------------------
__global__ __launch_bounds__(256) void dgnn_binscatter(const float* __restrict__ ew,
        const int* __restrict__ srcI, const int* __restrict__ dstI,
        int* __restrict__ binCur, int2* __restrict__ binned, int E, int NBINS) {
    __shared__ int hist[MAXBINS2];
    __shared__ int epk[EPB];              // packed (d | s<<16)
    __shared__ int ewb[EPB];              // sigmoid weight bits
    const int nb2 = 2 * NBINS;
    for (int i = threadIdx.x; i < nb2; i += 256) hist[i] = 0;
    __syncthreads();
    int base = blockIdx.x * EPB;
    int end = min(base + EPB, E);
    int cnt = end - base;
    for (int j = threadIdx.x; j < cnt; j += 256) {
        int e = base + j;
        int d = dstI[e], s = srcI[e];
        float x = ew[e];
        float w = 1.0f / (1.0f + expf(-x));
        epk[j] = d | (s << 16);
        ewb[j] = __float_as_int(w);
        atomicAdd(&hist[d >> BINSHIFT], 1);
        atomicAdd(&hist[NBINS + (s >> BINSHIFT)], 1);
    }
    __syncthreads();
    for (int i = threadIdx.x; i < nb2; i += 256) {
        int c = hist[i];
        int st = c ? atomicAdd(&binCur[i], c) : 0;    // claim block's range
        hist[i] = i * CAP + st;                       // global write cursor
    }
    __syncthreads();
    for (int j = threadIdx.x; j < cnt; j += 256) {
        int pk = epk[j];
        int wb = ewb[j];
        int d = pk & 0xffff, s = (pk >> 16) & 0xffff;
        int pd = atomicAdd(&hist[d >> BINSHIFT], 1);
        binned[pd] = make_int2(pk, wb);
        int ps = atomicAdd(&hist[NBINS + (s >> BINSHIFT)], 1);
        binned[ps] = make_int2(pk, wb);
    }
}

// ---------------------------------------------------------------------------
// CSR finalize: one block per bin; per-node offsets via 256-wide scan.
// Final CSR entry is 4B: nbr | (w_f16 << 16).
// ---------------------------------------------------------------------------
__global__ __launch_bounds__(256) void dgnn_csrfinal(const int2* __restrict__ binned,
        const int* __restrict__ binCur,
        int* __restrict__ offsD, int* __restrict__ degD,
        int* __restrict__ offsS, int* __restrict__ degS,
        unsigned int* __restrict__ nbrPD, unsigned int* __restrict__ nbrPS,
        int N, int NBINS) {
    int b = blockIdx.x;
    bool isD = b < NBINS;
    int lb = isD ? b : b - NBINS;
    int nodeBase = lb << BINSHIFT;
    const int2* bin = binned + (size_t)b * CAP;
    int K = binCur[b]; if (K > CAP) K = CAP;
    int* offs = isD ? offsD : offsS;
    int* dga  = isD ? degD : degS;
    unsigned int* out = (isD ? nbrPD : nbrPS) + (size_t)lb * CAP;

    __shared__ int cnt[BINSZ], cur[BINSZ], scanb[BINSZ];
    cnt[threadIdx.x] = 0;
    __syncthreads();
    for (int i = threadIdx.x; i < K; i += 256) {
        int pk = bin[i].x;
        int node = isD ? (pk & 0xffff) : ((pk >> 16) & 0xffff);
        atomicAdd(&cnt[node - nodeBase], 1);
    }
    __syncthreads();
    int v = cnt[threadIdx.x];
    scanb[threadIdx.x] = v;
    __syncthreads();
#pragma unroll
    for (int o = 1; o < 256; o <<= 1) {
        int u = (threadIdx.x >= o) ? scanb[threadIdx.x - o] : 0;
        __syncthreads();
        scanb[threadIdx.x] += u;
        __syncthreads();
    }
    int pos = scanb[threadIdx.x] - v;     // local exclusive prefix
    cur[threadIdx.x] = pos;
    int n = nodeBase + threadIdx.x;
    if (n < N) { offs[n] = lb * CAP + pos; dga[n] = v; }
    __syncthreads();
    for (int i = threadIdx.x; i < K; i += 256) {
        int2 en = bin[i];
        int node, nbr;
        if (isD) { node = en.x & 0xffff; nbr = (en.x >> 16) & 0xffff; }
        else     { node = (en.x >> 16) & 0xffff; nbr = en.x & 0xffff; }
        int p = atomicAdd(&cur[node - nodeBase], 1);
        unsigned short wh = f2h(__int_as_float(en.y));
        out[p] = (unsigned int)nbr | ((unsigned int)wh << 16);
    }
}

// ---------------------------------------------------------------------------
// Fused D+S aggregation (f16): one HALF-WAVE per node; packed 4B CSR entries.
// Main loop: 16 edges, 8 rows in flight per 16-lane group. Tail loop: 4 edges.
// ---------------------------------------------------------------------------
__global__ __launch_bounds__(256, 8) void dgnn_gather2(
        const unsigned short* __restrict__ xbD, const int* __restrict__ offsD,
        const int* __restrict__ degD, const unsigned int* __restrict__ nbrD,
        unsigned short* __restrict__ meanD,
        const unsigned short* __restrict__ xbS, const int* __restrict__ offsS,
        const int* __restrict__ degS, const unsigned int* __restrict__ nbrS,
        unsigned short* __restrict__ meanS,
        int N, int halfb) {
    int which = (blockIdx.x >= halfb) ? 1 : 0;
    const unsigned short* xb = which ? xbS : xbD;
    const int* offs          = which ? offsS : offsD;
    const int* dga           = which ? degS : degD;
    const unsigned int* nbrP = which ? nbrS : nbrD;
    unsigned short* meanb    = which ? meanS : meanD;

    long long gid = (long long)(blockIdx.x - which * halfb) * 256 + threadIdx.x;
    int n = (int)(gid >> 5);             // half-wave index = node
    if (n >= N) return;
    const int l32 = (int)gid & 31;       // lane within half
    const int q2  = l32 >> 4;            // group 0/1 (pair parity)
    const int m   = l32 & 15;            // channels m*8 .. m*8+7

    int beg = offs[n];
    int dg  = dga[n];
    int end = beg + dg;
    float acc[8];
#pragma unroll
    for (int k = 0; k < 8; k++) acc[k] = 0.f;

    for (int base = beg; base < end; base += 32) {
        int cnt = end - base; if (cnt > 32) cnt = 32;
        bool inb = (base + l32) < end;
        unsigned int pk_l = inb ? nbrP[base + l32] : 0u;   // nbr | w_f16<<16

        int it = 0;
        for (; it + 16 <= cnt; it += 16) {
            // group q2 handles pairs (e,e+1) at e = it+2*q2 + {0,4,8,12}
            int e0 = it + (q2 << 1);
            unsigned int p[8];
#pragma unroll
            for (int j = 0; j < 4; j++) {
                p[2 * j]     = __shfl(pk_l, e0 + 4 * j, 32);
                p[2 * j + 1] = __shfl(pk_l, e0 + 4 * j + 1, 32);
            }
            u32x4 v[8];
#pragma unroll
            for (int j = 0; j < 8; j++)
                v[j] = *(const u32x4*)(xb + ((size_t)(p[j] & 0xffffu) << 7) + (m << 3));
#pragma unroll
            for (int j = 0; j < 4; j++) {
                h16x2 wp = __builtin_bit_cast(h16x2,
                    __builtin_amdgcn_perm(p[2 * j + 1], p[2 * j], 0x07060302u));
#pragma unroll
                for (int k = 0; k < 4; k++) {
                    unsigned int ua = v[2 * j][k];
                    unsigned int ub = v[2 * j + 1][k];
                    h16x2 lo = __builtin_bit_cast(h16x2,
                        __builtin_amdgcn_perm(ub, ua, 0x05040100u));
                    h16x2 hi = __builtin_bit_cast(h16x2,
                        __builtin_amdgcn_perm(ub, ua, 0x07060302u));
                    acc[2 * k]     = dot2(wp, lo, acc[2 * k]);
                    acc[2 * k + 1] = dot2(wp, hi, acc[2 * k + 1]);
                }
            }
        }
        for (; it < cnt; it += 4) {      // 4-edge tail: 1 pair per group
            int e0 = it + (q2 << 1);     // pad lanes carry w=0, safe
            unsigned int pa = __shfl(pk_l, e0, 32);
            unsigned int pb = __shfl(pk_l, e0 + 1, 32);
            u32x4 va = *(const u32x4*)(xb + ((size_t)(pa & 0xffffu) << 7) + (m << 3));
            u32x4 vb = *(const u32x4*)(xb + ((size_t)(pb & 0xffffu) << 7) + (m << 3));
            h16x2 wp = __builtin_bit_cast(h16x2,
                __builtin_amdgcn_perm(pb, pa, 0x07060302u));
#pragma unroll
            for (int k = 0; k < 4; k++) {
                h16x2 lo = __builtin_bit_cast(h16x2,
                    __builtin_amdgcn_perm(vb[k], va[k], 0x05040100u));
                h16x2 hi = __builtin_bit_cast(h16x2,
                    __builtin_amdgcn_perm(vb[k], va[k], 0x07060302u));
                acc[2 * k]     = dot2(wp, lo, acc[2 * k]);
                acc[2 * k + 1] = dot2(wp, hi, acc[2 * k + 1]);
            }
        }
    }

#pragma unroll
    for (int k = 0; k < 8; k++)
        acc[k] += __shfl_xor(acc[k], 16);    // combine the two 16-groups

    if (q2 == 0) {
        float inv = 1.0f / fmaxf((float)dg, 1.0f);
        u16x8 o;
#pragma unroll
        for (int k = 0; k < 8; k++) o[k] = f2h(acc[k] * inv);
        *(u16x8*)(meanb + ((size_t)n << 7) + (m << 3)) = o;
    }
}

// ---------------------------------------------------------------------------
// Fused pair of node GEMMs via f16 MFMA, weight-stationary LDS (XOR-swizzled).
// ---------------------------------------------------------------------------
__global__ __launch_bounds__(256) void dgnn_node2(
        const unsigned short* __restrict__ meanA, const unsigned short* __restrict__ xbA,
        const unsigned short* __restrict__ WcA, const float* __restrict__ biasA,
        float* __restrict__ outfA, unsigned short* __restrict__ outbA,
        const unsigned short* __restrict__ meanB, const unsigned short* __restrict__ xbB,
        const unsigned short* __restrict__ WcB, const float* __restrict__ biasB,
        float* __restrict__ outfB, unsigned short* __restrict__ outbB,
        int N, int mode, int halfb) {
    __shared__ __align__(16) unsigned short sW[128 * 256];   // 64KB

    int which = (blockIdx.x >= halfb) ? 1 : 0;
    const unsigned short* meanb = which ? meanB : meanA;
    const unsigned short* xb    = which ? xbB : xbA;
    const unsigned short* Wc    = which ? WcB : WcA;
    const float* bias           = which ? biasB : biasA;
    float* outf                 = which ? outfB : outfA;
    unsigned short* outb        = which ? outbB : outbA;
    int lb = blockIdx.x - which * halfb;

    // ---- stage Wc (swizzled): 4096 16B chunks, coalesced reads
    for (int i = threadIdx.x; i < 4096; i += 256) {
        int ch = i >> 5;                 // 32 chunks per 512B row
        int off = (i & 31) << 4;
        float4 v = *(const float4*)((const char*)Wc + ((size_t)i << 4));
        int soff = off ^ ((ch & 7) << 4);
        *(float4*)((char*)sW + ch * 512 + soff) = v;
    }
    __syncthreads();

    const int wid = threadIdx.x >> 6;
    const int lane = threadIdx.x & 63;
    const int r = lane & 15;
    const int q = lane >> 4;
    const int ntiles = (N + 15) >> 4;

    for (int tile = lb * 4 + wid; tile < ntiles; tile += halfb * 4) {
        const int n0 = tile << 4;
        const unsigned short* A0 = meanb + (size_t)(n0 + r) * DIM + q * 8;
        const unsigned short* A1 = xb    + (size_t)(n0 + r) * DIM + q * 8;

        f32x4 acc[8];
#pragma unroll
        for (int ct = 0; ct < 8; ct++) acc[ct] = (f32x4){0.f, 0.f, 0.f, 0.f};

#pragma unroll
        for (int ks = 0; ks < 8; ks++) {
            h16x8 a = (ks < 4) ? *(const h16x8*)(A0 + ks * 32)
                               : *(const h16x8*)(A1 + (ks - 4) * 32);
#pragma unroll
            for (int ct = 0; ct < 8; ct++) {
                int ch = ct * 16 + r;
                int soff = (ks * 64 + q * 16) ^ ((ch & 7) << 4);
                h16x8 b = *(const h16x8*)((const char*)sW + ch * 512 + soff);
                acc[ct] = __builtin_amdgcn_mfma_f32_16x16x32_f16(a, b, acc[ct], 0, 0, 0);
            }
        }

#pragma unroll
        for (int ct = 0; ct < 8; ct++) {
            int ch = ct * 16 + r;
            float bv = bias[ch];
#pragma unroll
            for (int rr = 0; rr < 4; rr++) {
                int n = n0 + q * 4 + rr;
                if (n >= N) break;
                float v = acc[ct][rr] + bv;
                if (mode) {
                    v = fmaxf(v, 0.f);
                    outb[(size_t)n * DIM + ch] = f2h(v);
                } else {
                    outf[(size_t)n * DIM + ch] = v;
                }
            }
        }
    }
}

// ---------------------------------------------------------------------------
extern "C" void kernel_launch(void* const* d_in, const int* in_sizes, int n_in,
                              void* d_out, int out_size, void* d_ws, size_t ws_size,
                              hipStream_t stream) {
    const float* s  = (const float*)d_in[0];
    const float* t  = (const float*)d_in[1];
    const int*   ei = (const int*)d_in[2];   // [2,E] int32 per harness ABI
    const float* ew = (const float*)d_in[3];
    const float* s0_Wl = (const float*)d_in[4];
    const float* s0_bl = (const float*)d_in[5];
    const float* s0_Wr = (const float*)d_in[6];
    const float* t0_Wl = (const float*)d_in[7];
    const float* t0_bl = (const float*)d_in[8];
    const float* t0_Wr = (const float*)d_in[9];
    const float* s1_Wl = (const float*)d_in[10];
    const float* s1_bl = (const float*)d_in[11];
    const float* s1_Wr = (const float*)d_in[12];
    const float* t1_Wl = (const float*)d_in[13];
    const float* t1_bl = (const float*)d_in[14];
    const float* t1_Wr = (const float*)d_in[15];

    const int N = in_sizes[0] / DIM;
    const int E = in_sizes[3];
    const int NBINS = (N + BINSZ - 1) / BINSZ;

    // ---- workspace carve-up
    unsigned int* nbrPD = (unsigned int*)d_ws;          // [NBINS*CAP] packed
    unsigned int* nbrPS = nbrPD + (size_t)NBINS * CAP;  // [NBINS*CAP]
    unsigned short* up = (unsigned short*)(nbrPS + (size_t)NBINS * CAP);
    unsigned short* sb    = up;                         // [N*128] f16
    unsigned short* tb    = sb    + (size_t)N * DIM;
    unsigned short* meanA = tb    + (size_t)N * DIM;    // aliased: binned
    unsigned short* meanB = meanA + (size_t)N * DIM;
    unsigned short* s1b   = meanB + (size_t)N * DIM;
    unsigned short* t1b   = s1b   + (size_t)N * DIM;
    unsigned short* Wc    = t1b   + (size_t)N * DIM;    // [4*128*256] f16
    int* ip     = (int*)(Wc + 4 * 128 * 256);
    int* binCur = ip;                                   // [2*NBINS]
    int* offsD  = binCur + 2 * NBINS;                   // [N]
    int* degD   = offsD + N;                            // [N]
    int* offsS  = degD + N;                             // [N]
    int* degS   = offsS + N;                            // [N]

    int2* binned = (int2*)meanA;    // [2*NBINS*CAP] = 19.3MB <= meanA+meanB

    float* sout = (float*)d_out;
    float* tout = sout + (size_t)N * DIM;

    const int* srcI = ei;       // row 0
    const int* dstI = ei + E;   // row 1

    const int binb = (E + EPB - 1) / EPB;
    const int gbH = (int)(((long long)N * 32 + 255) / 256);   // half-wave/node
    const int nodeb = 256;                              // per conv; grid 512
    const int cvtb = ((N * DIM / 4) + 255) / 256;

    // ---- prep: f16 conversions (features + weights) + binCur zero, one launch
    WPtrs wp;
    wp.Wl[0] = s0_Wl; wp.Wr[0] = s0_Wr;
    wp.Wl[1] = t0_Wl; wp.Wr[1] = t0_Wr;
    wp.Wl[2] = s1_Wl; wp.Wr[2] = s1_Wr;
    wp.Wl[3] = t1_Wl; wp.Wr[3] = t1_Wr;
    dgnn_prep<<<2 * cvtb + 129, 256, 0, stream>>>(s, t, sb, tb, N * DIM / 4,
                                                  cvtb, wp, Wc, 2 * cvtb,
                                                  binCur, 2 * NBINS);

    // ---- CSR build: fixed-capacity bucket scatter + per-bin finalize
    dgnn_binscatter<<<binb, 256, 0, stream>>>(ew, srcI, dstI, binCur, binned, E, NBINS);
    dgnn_csrfinal<<<2 * NBINS, 256, 0, stream>>>(binned, binCur,
                                                 offsD, degD, offsS, degS,
                                                 nbrPD, nbrPS, N, NBINS);

    // ---- layer 0 (relu, f16 intermediates)
    dgnn_gather2<<<2 * gbH, 256, 0, stream>>>(tb, offsD, degD, nbrPD, meanA,
                                              sb, offsS, degS, nbrPS, meanB, N, gbH);
    dgnn_node2<<<2 * nodeb, 256, 0, stream>>>(
        meanA, tb, Wc,         s0_bl, nullptr, s1b,
        meanB, sb, Wc + 32768, t0_bl, nullptr, t1b, N, 1, nodeb);

    // ---- layer 1 (f32 outputs)
    dgnn_gather2<<<2 * gbH, 256, 0, stream>>>(t1b, offsD, degD, nbrPD, meanA,
                                              s1b, offsS, degS, nbrPS, meanB, N, gbH);
    dgnn_node2<<<2 * nodeb, 256, 0, stream>>>(
        meanA, t1b, Wc + 2 * 32768, s1_bl, sout, nullptr,
        meanB, s1b, Wc + 3 * 32768, t1_bl, tout, nullptr, N, 0, nodeb);
}